// Round 3
// baseline (185.576 us; speedup 1.0000x reference)
//
#include <hip/hip_runtime.h>

// MultiScaleSampler R10: workspace-free pipeline (kill the 256MiB ws poison).
// R9 post-mortem: harness poisons the FULL workspace (256MiB fill, ~45us)
// inside the timed graph whenever d_ws is used. So: move the feat scratch
// INTO out itself at stride-3 words (out_u32[3*pixel]) — every read/write of
// the intermediate is wave-private (wave owns pixels [i0,i0+128) and words
// [3*i0, 3*i0+384)), so no cross-block hazard exists.
// Pipeline: memset(out, 0xFF) -> scatter packed (f16 fx, f16 fy) via
// nontemporal 4B stores to out_u32[3*yi] -> dense per-pixel MLP reads its
// own feat words, computes, overwrites its range densely (zeros at sentinel).
// MFMA MLP core + paired-softmax tail verbatim from harness-verified R9;
// each block now processes 1024 pixels (2 groups) to amortize the weight
// prologue.

#define W_IMG 2048
#define NF    32

typedef __attribute__((ext_vector_type(8))) _Float16 f16x8;
typedef __attribute__((ext_vector_type(4))) _Float16 f16x4;
typedef __attribute__((ext_vector_type(4))) float    f32x4;
typedef __attribute__((ext_vector_type(4))) float    fvec4;
typedef __attribute__((ext_vector_type(4))) int      ivec4;

static __device__ __forceinline__ unsigned packfeat(float fx, float fy) {
    unsigned short ux = __builtin_bit_cast(unsigned short, (_Float16)fx);
    unsigned short uy = __builtin_bit_cast(unsigned short, (_Float16)fy);
    return ((unsigned)uy << 16) | (unsigned)ux;
}

// K1: scatter packed fractional coords into out_u32[3*pixel].
// Valid packs never equal 0xFFFFFFFF (f16(fy) is never NaN-patterned).
// Nontemporal: 4B random writes, skip L2 write-allocate/RFO thrash.
__global__ __launch_bounds__(256) void scatter_feat(
    const float* __restrict__ grid, const int* __restrict__ yi,
    unsigned* __restrict__ outw, int N)
{
    int t = blockIdx.x * blockDim.x + threadIdx.x;
    int stride = gridDim.x * blockDim.x;
    if ((N & 3) == 0) {
        int n4 = N >> 2;
        const fvec4* gx4 = (const fvec4*)grid;
        const fvec4* gy4 = (const fvec4*)(grid + N);
        const ivec4* yi4 = (const ivec4*)yi;
        for (int j = t; j < n4; j += stride) {
            fvec4 x = __builtin_nontemporal_load((fvec4*)(gx4 + j));
            fvec4 y = __builtin_nontemporal_load((fvec4*)(gy4 + j));
            ivec4 p = __builtin_nontemporal_load((ivec4*)(yi4 + j));
#pragma unroll
            for (int k = 0; k < 4; ++k) {
                float fx = x[k] - floorf(x[k]);
                float fy = y[k] - floorf(y[k]);
                __builtin_nontemporal_store(packfeat(fx, fy), outw + 3 * p[k]);
            }
        }
    } else {
        for (int i = t; i < N; i += stride) {
            float gx = grid[i], gy = grid[N + i];
            __builtin_nontemporal_store(packfeat(gx - floorf(gx), gy - floorf(gy)),
                                        outw + 3 * yi[i]);
        }
    }
}

static __device__ __forceinline__ void softmax3(f32x4 L, bool v, float* r) {
    float mx = fmaxf(L[0], fmaxf(L[1], L[2]));
    float e0 = __expf(L[0] - mx);
    float e1 = __expf(L[1] - mx);
    float e2 = __expf(L[2] - mx);
    float inv = __builtin_amdgcn_rcpf(e0 + e1 + e2);
    r[0] = v ? e0 * inv : 0.f;
    r[1] = v ? e1 * inv : 0.f;
    r[2] = v ? e2 * inv : 0.f;
}

// K2: dense per-pixel MLP. 1024 pixels/block (2 groups x 4 waves x 128),
// wave-private LDS, zero barriers. Feat words read/written wave-privately.
__global__ __launch_bounds__(256, 4) void msampler_mlp(
    const float* __restrict__ m,          // (3,3)
    const float* __restrict__ W1, const float* __restrict__ b1,   // (5,32),(32)
    const float* __restrict__ W2, const float* __restrict__ b2,   // (32,32),(32)
    const float* __restrict__ W3, const float* __restrict__ b3,   // (32,32),(32)
    const float* __restrict__ W4, const float* __restrict__ b4,   // (32,3),(3)
    float* __restrict__ out, int HW)
{
    const int tid  = threadIdx.x;
    const int lane = tid & 63;
    const int wave = tid >> 6;
    const int lm   = lane & 15;
    const int lq   = lane >> 4;
    const unsigned* __restrict__ outw = (const unsigned*)out;

    __shared__ __align__(16) char smem[4 * 8192];
    char* buf = smem + wave * 8192;   // 8 tiles x 1024B, wave-private

    // ---- one-time weight fragments (A = W^T: A[m=out][k=in]) ----
    f16x8 a1[2], a2[2], a3[2], a4;
    f32x4 cb1[2], cb2[2], cb3[2], cb4;
#pragma unroll
    for (int mh = 0; mh < 2; ++mh) {
        int outc = 16 * mh + lm;
#pragma unroll
        for (int j = 0; j < 8; ++j) {
            int k = lq * 8 + j;
            a1[mh][j] = (k < 5) ? (_Float16)W1[k * NF + outc] : (_Float16)0.0f;
            a2[mh][j] = (_Float16)W2[k * NF + outc];
            a3[mh][j] = (_Float16)W3[k * NF + outc];
        }
#pragma unroll
        for (int r = 0; r < 4; ++r) {
            int o = 16 * mh + lq * 4 + r;
            cb1[mh][r] = b1[o];
            cb2[mh][r] = b2[o];
            cb3[mh][r] = b3[o];
        }
    }
#pragma unroll
    for (int j = 0; j < 8; ++j) {
        int k = lq * 8 + j;
        a4[j] = (lm < 3) ? (_Float16)W4[k * 3 + lm] : (_Float16)0.0f;
    }
#pragma unroll
    for (int r = 0; r < 4; ++r) {
        int o = lq * 4 + r;
        cb4[r] = (o < 3) ? b4[o] : 0.f;
    }

    // ---- uniform homography scalars ----
    float m00=m[0], m01=m[1], m02=m[2];
    float m10=m[3], m11=m[4], m12=m[5];
    float m20=m[6], m21=m[7], m22=m[8];
    float det = m00*(m11*m22 - m12*m21)
              - m01*(m10*m22 - m12*m20)
              + m02*(m10*m21 - m11*m20);
    float adet = fabsf(det);

    // write offset for D-frag (mh, tile T): consumer lane (2mh + lq/2, lm),
    // half (lq&1)
    const int woff = ((lq >> 1) * 16 + lm) * 16 + (lq & 1) * 8;

    const int base = blockIdx.x * 1024;

#pragma unroll 1
    for (int grp = 0; grp < 2; ++grp) {
        const int i0 = base + grp * 512 + wave * 128;
        if (i0 >= HW) break;

        // ---- features for 2 pixels/lane from own feat words; write B-frag ----
#pragma unroll
        for (int t = 0; t < 2; ++t) {
            int s  = i0 + t * 64 + lane;
            int sc = s < HW ? s : HW - 1;
            unsigned w = outw[3 * sc];
            int py = sc >> 11;            // / 2048
            int px = sc & (W_IMG - 1);    // % 2048
            float denom = m20*(float)px + m21*(float)py + m22;
            float ad    = fabsf(denom);
            float ad3   = ad * ad * ad;
            float dsda  = fminf(adet * __builtin_amdgcn_rcpf(ad3), 60000.f);
            _Float16 hx = __builtin_bit_cast(_Float16, (unsigned short)(w & 0xFFFFu));
            _Float16 hy = __builtin_bit_cast(_Float16, (unsigned short)(w >> 16));
            float fxf = (float)hx, fyf = (float)hy;
            f16x8 f;
            f[0] = hx;                   f[1] = hy;
            f[2] = (_Float16)(1.f-fxf);  f[3] = (_Float16)(1.f-fyf);
            f[4] = (_Float16)dsda;       f[5] = (_Float16)0.0f;
            f[6] = (_Float16)0.0f;       f[7] = (_Float16)0.0f;
            int g = t * 4 + lq;          // tile of this pixel
            *(f16x8*)(buf + g * 1024 + lm * 16) = f;   // consumer slot (lq_c=0, lm)
        }
        // zero k=8..31 regions of all 8 tiles (48 chunks x 16B per tile)
        {
            f16x8 z = {};
#pragma unroll
            for (int j = 0; j < 6; ++j) {
                int T  = lane >> 3;
                int ch = (lane & 7) + 8 * j;
                *(f16x8*)(buf + T * 1024 + 256 + ch * 16) = z;
            }
        }

        // ---- layers 1..3: read B-frags, MFMA, relu+clamp+cvt, write frags ----
#define LAYER(AF, CB)                                                          \
        _Pragma("unroll")                                                      \
        for (int tg = 0; tg < 2; ++tg) {                                       \
            f16x8 bf[4];                                                       \
            _Pragma("unroll")                                                  \
            for (int q = 0; q < 4; ++q)                                        \
                bf[q] = *(const f16x8*)(buf + (tg*4 + q) * 1024 + lane * 16);  \
            _Pragma("unroll")                                                  \
            for (int q = 0; q < 4; ++q) {                                      \
                int T = tg * 4 + q;                                            \
                _Pragma("unroll")                                              \
                for (int mh = 0; mh < 2; ++mh) {                               \
                    f32x4 d = __builtin_amdgcn_mfma_f32_16x16x32_f16(          \
                        AF[mh], bf[q], CB[mh], 0, 0, 0);                       \
                    f16x4 o;                                                   \
                    _Pragma("unroll")                                          \
                    for (int r = 0; r < 4; ++r)                                \
                        o[r] = (_Float16)fminf(fmaxf(d[r], 0.f), 60000.f);     \
                    *(f16x4*)(buf + T * 1024 + mh * 512 + woff) = o;           \
                }                                                              \
            }                                                                  \
        }

        LAYER(a1, cb1)
        LAYER(a2, cb2)
        LAYER(a3, cb3)
#undef LAYER

        // ---- layer 4: one MFMA per tile; logits (rows 0..2) in lq==0 lanes;
        //      stash to pixel-indexed slots (first 2KB, tiles consumed) ----
#pragma unroll
        for (int tg = 0; tg < 2; ++tg) {
            f16x8 bf[4];
#pragma unroll
            for (int q = 0; q < 4; ++q)
                bf[q] = *(const f16x8*)(buf + (tg*4 + q) * 1024 + lane * 16);
#pragma unroll
            for (int q = 0; q < 4; ++q) {
                int T = tg * 4 + q;
                f32x4 d = __builtin_amdgcn_mfma_f32_16x16x32_f16(a4, bf[q], cb4, 0, 0, 0);
                if (lq == 0)
                    *(f32x4*)(buf + (T * 16 + lm) * 16) = d;   // slot s = T*16+lm
            }
        }

        // ---- paired-pixel softmax + coalesced write (zeros at sentinel) ----
        {
            int s0 = 2 * lane;              // wave-local pixel pair (s0, s0+1)
            int g0 = i0 + s0;
            unsigned v0, v1;
            if (g0 + 1 < HW) {
                v0 = outw[3 * g0];          // own words, L2-hot, pre-overwrite
                v1 = outw[3 * g0 + 3];
            } else {
                int gc = g0 < HW ? g0 : HW - 1;
                v0 = outw[3 * gc]; v1 = v0;
            }
            f32x4 L0 = *(const f32x4*)(buf + (s0    ) * 16);
            f32x4 L1 = *(const f32x4*)(buf + (s0 + 1) * 16);
            float r0[3], r1[3];
            softmax3(L0, v0 != 0xFFFFFFFFu, r0);
            softmax3(L1, v1 != 0xFFFFFFFFu, r1);
            if (g0 + 1 < HW) {
                float* o = out + (size_t)g0 * 3;   // 8B-aligned (24B*lane)
                *(float2*)(o + 0) = make_float2(r0[0], r0[1]);
                *(float2*)(o + 2) = make_float2(r0[2], r1[0]);
                *(float2*)(o + 4) = make_float2(r1[1], r1[2]);
            } else if (g0 < HW) {
                float* o = out + (size_t)g0 * 3;
                o[0] = r0[0]; o[1] = r0[1]; o[2] = r0[2];
            }
        }
    }
}

extern "C" void kernel_launch(void* const* d_in, const int* in_sizes, int n_in,
                              void* d_out, int out_size, void* d_ws, size_t ws_size,
                              hipStream_t stream) {
    const float* grid = (const float*)d_in[0];
    const int*   yi   = (const int*)  d_in[1];
    const float* m    = (const float*)d_in[2];
    const float* W1   = (const float*)d_in[3];
    const float* b1   = (const float*)d_in[4];
    const float* W2   = (const float*)d_in[5];
    const float* b2   = (const float*)d_in[6];
    const float* W3   = (const float*)d_in[7];
    const float* b3   = (const float*)d_in[8];
    const float* W4   = (const float*)d_in[9];
    const float* b4   = (const float*)d_in[10];
    float* out = (float*)d_out;

    int N  = in_sizes[1];      // number of sampled points
    int HW = out_size / 3;     // number of output pixels

    // sentinel init of the whole output (0xFFFFFFFF never a valid pack)
    hipMemsetAsync(d_out, 0xFF, (size_t)out_size * sizeof(float), stream);

    int sblocks = ((N >> 2) + 255) / 256;
    if (sblocks < 1) sblocks = 1;
    if (sblocks > 4096) sblocks = 4096;
    scatter_feat<<<sblocks, 256, 0, stream>>>(grid, yi, (unsigned*)d_out, N);

    int blocks = (HW + 1023) / 1024;   // 1024 pixels per block
    msampler_mlp<<<blocks, 256, 0, stream>>>(
        m, W1, b1, W2, b2, W3, b3, W4, b4, out, HW);
}

// Round 4
// 134.578 us; speedup vs baseline: 1.3790x; 1.3790x over previous
//
#include <hip/hip_runtime.h>

// MultiScaleSampler R11: R7 fused kernel + minimum-random-tax write.
// Measured facts driving this: random sector ceiling ~1.1-1.2 TB/s (R7/R10);
// L2 is no-write-allocate (R7 FETCH 9.4MB vs 63.6MB writes) so scatters never
// merge; 256MiB ws-poison (~45us) appears unconditional (R10 totals).
// So: pay the permutation ONCE at 32B/pt (4B packed store to ws[yi], 8.4MB
// region — R9 measured this pattern <43us), then a trivial dense expand pass
// (uint4 -> 3x float4, sentinel -> zeros) replaces fill_zero + wide scatter.
// MLP core verbatim from harness-verified R7.

#define W_IMG 2048
#define NF    32

typedef __attribute__((ext_vector_type(8))) _Float16 f16x8;
typedef __attribute__((ext_vector_type(4))) _Float16 f16x4;
typedef __attribute__((ext_vector_type(4))) float    f32x4;

// K1: per-point fused feature+MLP+softmax, packed (f16 w0, f16 w1) -> ws[yi].
__global__ __launch_bounds__(256, 4) void msampler_mlp(
    const float* __restrict__ grid,   // (2, N)
    const int*   __restrict__ yi,     // (N,)
    const float* __restrict__ m,      // (3,3)
    const float* __restrict__ W1, const float* __restrict__ b1,   // (5,32),(32)
    const float* __restrict__ W2, const float* __restrict__ b2,   // (32,32),(32)
    const float* __restrict__ W3, const float* __restrict__ b3,   // (32,32),(32)
    const float* __restrict__ W4, const float* __restrict__ b4,   // (32,3),(3)
    unsigned* __restrict__ wsp, int N)
{
    const int tid  = threadIdx.x;
    const int lane = tid & 63;
    const int wave = tid >> 6;
    const int lm   = lane & 15;
    const int lq   = lane >> 4;

    __shared__ __align__(16) char smem[4 * 8192];
    char* buf = smem + wave * 8192;   // 8 tiles x 1024B, wave-private

    // ---- one-time weight fragments (A = W^T: A[m=out][k=in]) ----
    f16x8 a1[2], a2[2], a3[2], a4;
    f32x4 cb1[2], cb2[2], cb3[2], cb4;
#pragma unroll
    for (int mh = 0; mh < 2; ++mh) {
        int outc = 16 * mh + lm;
#pragma unroll
        for (int j = 0; j < 8; ++j) {
            int k = lq * 8 + j;
            a1[mh][j] = (k < 5) ? (_Float16)W1[k * NF + outc] : (_Float16)0.0f;
            a2[mh][j] = (_Float16)W2[k * NF + outc];
            a3[mh][j] = (_Float16)W3[k * NF + outc];
        }
#pragma unroll
        for (int r = 0; r < 4; ++r) {
            int o = 16 * mh + lq * 4 + r;
            cb1[mh][r] = b1[o];
            cb2[mh][r] = b2[o];
            cb3[mh][r] = b3[o];
        }
    }
#pragma unroll
    for (int j = 0; j < 8; ++j) {
        int k = lq * 8 + j;
        a4[j] = (lm < 3) ? (_Float16)W4[k * 3 + lm] : (_Float16)0.0f;
    }
#pragma unroll
    for (int r = 0; r < 4; ++r) {
        int o = lq * 4 + r;
        cb4[r] = (o < 3) ? b4[o] : 0.f;
    }

    // ---- uniform homography scalars ----
    float m00=m[0], m01=m[1], m02=m[2];
    float m10=m[3], m11=m[4], m12=m[5];
    float m20=m[6], m21=m[7], m22=m[8];
    float det = m00*(m11*m22 - m12*m21)
              - m01*(m10*m22 - m12*m20)
              + m02*(m10*m21 - m11*m20);
    float adet = fabsf(det);

    // ---- features for 2 points (slots s = t*64 + lane), write B-frag slot ----
    const int i0 = blockIdx.x * 512 + wave * 128;
    int ya[2];
#pragma unroll
    for (int t = 0; t < 2; ++t) {
        int i  = i0 + t * 64 + lane;
        int ic = i < N ? i : N - 1;
        float gx = grid[ic];
        float gy = grid[N + ic];
        int   y  = yi[ic];
        ya[t] = y;
        int py = y >> 11;            // / 2048
        int px = y & (W_IMG - 1);    // % 2048
        float denom = m20*(float)px + m21*(float)py + m22;
        float ad    = fabsf(denom);
        float dsda  = fminf(adet * __builtin_amdgcn_rcpf(ad*ad*ad), 60000.f);
        float fx = gx - floorf(gx);
        float fy = gy - floorf(gy);
        f16x8 f;
        f[0] = (_Float16)fx;         f[1] = (_Float16)fy;
        f[2] = (_Float16)(1.f-fx);   f[3] = (_Float16)(1.f-fy);
        f[4] = (_Float16)dsda;       f[5] = (_Float16)0.0f;
        f[6] = (_Float16)0.0f;       f[7] = (_Float16)0.0f;
        int g = t * 4 + lq;          // tile of this point
        *(f16x8*)(buf + g * 1024 + lm * 16) = f;   // consumer slot (lq_c=0, lm)
    }
    // zero k=8..31 regions of all 8 tiles (48 chunks x 16B per tile)
    {
        f16x8 z = {};
#pragma unroll
        for (int j = 0; j < 6; ++j) {
            int T  = lane >> 3;
            int ch = (lane & 7) + 8 * j;
            *(f16x8*)(buf + T * 1024 + 256 + ch * 16) = z;
        }
    }

    // write offset for D-frag (mh, tile T): consumer lane (2mh + lq/2, lm),
    // half (lq&1)
    const int woff = ((lq >> 1) * 16 + lm) * 16 + (lq & 1) * 8;

    // ---- layers 1..3: read B-frags, MFMA, relu+clamp+cvt, write frags ----
#define LAYER(AF, CB)                                                          \
    _Pragma("unroll")                                                          \
    for (int tg = 0; tg < 2; ++tg) {                                           \
        f16x8 bf[4];                                                           \
        _Pragma("unroll")                                                      \
        for (int q = 0; q < 4; ++q)                                            \
            bf[q] = *(const f16x8*)(buf + (tg*4 + q) * 1024 + lane * 16);      \
        _Pragma("unroll")                                                      \
        for (int q = 0; q < 4; ++q) {                                          \
            int T = tg * 4 + q;                                                \
            _Pragma("unroll")                                                  \
            for (int mh = 0; mh < 2; ++mh) {                                   \
                f32x4 d = __builtin_amdgcn_mfma_f32_16x16x32_f16(              \
                    AF[mh], bf[q], CB[mh], 0, 0, 0);                           \
                f16x4 o;                                                       \
                _Pragma("unroll")                                              \
                for (int r = 0; r < 4; ++r)                                    \
                    o[r] = (_Float16)fminf(fmaxf(d[r], 0.f), 60000.f);         \
                *(f16x4*)(buf + T * 1024 + mh * 512 + woff) = o;               \
            }                                                                  \
        }                                                                      \
    }

    LAYER(a1, cb1)
    LAYER(a2, cb2)
    LAYER(a3, cb3)
#undef LAYER

    // ---- layer 4: one MFMA per tile; logits (rows 0..2) sit in lq==0 lanes;
    //      stash to pt-indexed slots (first 2KB, tiles already consumed) ----
#pragma unroll
    for (int tg = 0; tg < 2; ++tg) {
        f16x8 bf[4];
#pragma unroll
        for (int q = 0; q < 4; ++q)
            bf[q] = *(const f16x8*)(buf + (tg*4 + q) * 1024 + lane * 16);
#pragma unroll
        for (int q = 0; q < 4; ++q) {
            int T = tg * 4 + q;
            f32x4 d = __builtin_amdgcn_mfma_f32_16x16x32_f16(a4, bf[q], cb4, 0, 0, 0);
            if (lq == 0)
                *(f32x4*)(buf + (T * 16 + lm) * 16) = d;   // pt slot, 16B
        }
    }

    // ---- softmax + single 4B packed scatter per point (32B sector min) ----
#pragma unroll
    for (int t = 0; t < 2; ++t) {
        int s = t * 64 + lane;
        f32x4 L = *(const f32x4*)(buf + s * 16);
        float l0 = L[0], l1 = L[1], l2 = L[2];
        float mx = fmaxf(l0, fmaxf(l1, l2));
        float e0 = __expf(l0 - mx), e1 = __expf(l1 - mx), e2 = __expf(l2 - mx);
        float inv = __builtin_amdgcn_rcpf(e0 + e1 + e2);
        int i = i0 + s;
        if (i < N) {
            unsigned short u0 =
                __builtin_bit_cast(unsigned short, (_Float16)(e0 * inv));
            unsigned short u1 =
                __builtin_bit_cast(unsigned short, (_Float16)(e1 * inv));
            wsp[ya[t]] = ((unsigned)u1 << 16) | (unsigned)u0;
        }
    }
}

// K2: dense expand. Lane: uint4 (4 px, 16B read) -> 3x float4 (48B write).
// Sentinel 0xFFFFFFFF (never a valid (f16,f16) pack, both in [0,1]) -> zeros.
__global__ __launch_bounds__(256) void expand_out(
    const unsigned* __restrict__ wsp, float* __restrict__ out, int HW)
{
    int t = blockIdx.x * blockDim.x + threadIdx.x;
    int stride = gridDim.x * blockDim.x;
    int n4 = HW >> 2;
    for (int j = t; j < n4; j += stride) {
        uint4 p = *(const uint4*)(wsp + 4 * j);
        unsigned pk[4] = {p.x, p.y, p.z, p.w};
        float w[12];
#pragma unroll
        for (int k = 0; k < 4; ++k) {
            bool v = pk[k] != 0xFFFFFFFFu;
            float w0 = (float)__builtin_bit_cast(_Float16,
                           (unsigned short)(pk[k] & 0xFFFFu));
            float w1 = (float)__builtin_bit_cast(_Float16,
                           (unsigned short)(pk[k] >> 16));
            float w2 = fmaxf(1.f - w0 - w1, 0.f);
            w[3*k + 0] = v ? w0 : 0.f;
            w[3*k + 1] = v ? w1 : 0.f;
            w[3*k + 2] = v ? w2 : 0.f;
        }
        float4* o = (float4*)(out + (size_t)12 * j);   // 48B-aligned
        o[0] = make_float4(w[0], w[1],  w[2],  w[3]);
        o[1] = make_float4(w[4], w[5],  w[6],  w[7]);
        o[2] = make_float4(w[8], w[9],  w[10], w[11]);
    }
    // tail (HW % 4)
    for (int r = (n4 << 2) + t; r < HW; r += stride) {
        unsigned pk = wsp[r];
        bool v = pk != 0xFFFFFFFFu;
        float w0 = (float)__builtin_bit_cast(_Float16, (unsigned short)(pk & 0xFFFFu));
        float w1 = (float)__builtin_bit_cast(_Float16, (unsigned short)(pk >> 16));
        out[3*r + 0] = v ? w0 : 0.f;
        out[3*r + 1] = v ? w1 : 0.f;
        out[3*r + 2] = v ? fmaxf(1.f - w0 - w1, 0.f) : 0.f;
    }
}

extern "C" void kernel_launch(void* const* d_in, const int* in_sizes, int n_in,
                              void* d_out, int out_size, void* d_ws, size_t ws_size,
                              hipStream_t stream) {
    const float* grid = (const float*)d_in[0];
    const int*   yi   = (const int*)  d_in[1];
    const float* m    = (const float*)d_in[2];
    const float* W1   = (const float*)d_in[3];
    const float* b1   = (const float*)d_in[4];
    const float* W2   = (const float*)d_in[5];
    const float* b2   = (const float*)d_in[6];
    const float* W3   = (const float*)d_in[7];
    const float* b3   = (const float*)d_in[8];
    const float* W4   = (const float*)d_in[9];
    const float* b4   = (const float*)d_in[10];
    float* out = (float*)d_out;

    int N  = in_sizes[1];      // number of sampled points
    int HW = out_size / 3;     // number of output pixels

    unsigned* wsp = (unsigned*)d_ws;

    // sentinel init (0xFFFFFFFF never a valid pack)
    hipMemsetAsync(d_ws, 0xFF, (size_t)HW * sizeof(unsigned), stream);

    int grid_sz = (N + 511) / 512;   // 512 points per block (4 waves x 128)
    msampler_mlp<<<grid_sz, 256, 0, stream>>>(
        grid, yi, m, W1, b1, W2, b2, W3, b3, W4, b4, wsp, N);

    int eblocks = ((HW >> 2) + 255) / 256;
    if (eblocks < 1) eblocks = 1;
    expand_out<<<eblocks, 256, 0, stream>>>(wsp, out, HW);
}